// Round 11
// baseline (587.985 us; speedup 1.0000x reference)
//
#include <hip/hip_runtime.h>
#include <hip/hip_bf16.h>

#define NSTEPS 20
#define BROWS  8192
#define LATENT 256
#define UDIM   16
#define HIDDEN 512
#define BM     32      // rows per block
#define XLD    296     // LDS row stride (bf16) for X (b128-friendly)
#define HLD    536     // LDS row stride (bf16) for H (b128-friendly)

// packed-weight footprint (shorts)
#define W1P_SHORTS (9 * 32 * 64 * 8)     // 147456
#define W2P_SHORTS (16 * 16 * 64 * 8)    // 131072

// Packed weights in module-scope device memory (load-time allocation; no
// hipMalloc, no d_ws, no d_out aliasing). Re-packed from immutable W1/W2
// every call -> deterministic across graph replays.
__device__ __align__(16) short g_Wpack[W1P_SHORTS + W2P_SHORTS];

typedef __attribute__((ext_vector_type(8))) short bf16x8;
typedef __attribute__((ext_vector_type(4))) short bf16x4;
typedef __attribute__((ext_vector_type(4))) float f32x4;

__device__ __forceinline__ short f2bf(float x) {
    union { __hip_bfloat16 h; short s; } u;
    u.h = __float2bfloat16(x);
    return u.s;
}

__device__ __forceinline__ float tanh_fast(float x) {
    float e = __expf(2.0f * x);
    return 1.0f - 2.0f * __builtin_amdgcn_rcpf(e + 1.0f);
}

// Pack W1 (272x512, K zero-padded to 288) and W2 (512x256) into per-fragment
// order: frag(kt,nt): lane l holds W[k = kt*32 + (l>>4)*8 + j][n = nt*16 + (l&15)].
__global__ void prep_weights(const float* __restrict__ W1, const float* __restrict__ W2) {
    short* W1p = g_Wpack;
    short* W2p = g_Wpack + W1P_SHORTS;
    int t = blockIdx.x * 256 + threadIdx.x;
    if (t < 9 * 32 * 64) {
        int l = t & 63, f = t >> 6;          // f: 0..287 = kt*32+nt
        int kt = f >> 5, nt = f & 31;
        int k0 = kt * 32 + ((l >> 4) << 3);
        int n = nt * 16 + (l & 15);
        bf16x8 o;
#pragma unroll
        for (int j = 0; j < 8; ++j) {
            int k = k0 + j;
            o[j] = (k < 272) ? f2bf(W1[k * 512 + n]) : (short)0;
        }
        *reinterpret_cast<bf16x8*>(W1p + t * 8) = o;
    } else if (t < 9 * 32 * 64 + 16 * 16 * 64) {
        int t2 = t - 9 * 32 * 64;
        int l = t2 & 63, f = t2 >> 6;        // f: 0..255 = kt*16+nt
        int kt = f >> 4, nt = f & 15;
        int k0 = kt * 32 + ((l >> 4) << 3);
        int n = nt * 16 + (l & 15);
        bf16x8 o;
#pragma unroll
        for (int j = 0; j < 8; ++j) o[j] = f2bf(W2[(k0 + j) * 256 + n]);
        *reinterpret_cast<bf16x8*>(W2p + t2 * 8) = o;
    }
}

// One block = 32 rows, 8 waves (hard cap: 256 unified regs/wave at 2 waves/SIMD).
// r11: per-GEMM BURST weight loading. All fragment loads for a GEMM issue as
// one batch (36 resp. 32 global_load_dwordx4 in flight), pinned via opacity
// asm at the point where the drain must complete. W2's flight overlaps
// tanh+H-write+barrier; next step's W1 flight overlaps z-update+X-write+
// barrier. Converts the sunk per-kt load pattern (4 in flight, latency-bound)
// into L2-BW-bound bursts. No cross-step residency (impossible: 544KB weights
// vs ~300KB pinnable RF).
__global__ __launch_bounds__(512, 2) void ode_kernel(
    const float* __restrict__ zt, const float* __restrict__ dtp,
    const float* __restrict__ ut, const float* __restrict__ b1,
    const float* __restrict__ b2, float* __restrict__ out) {
    __shared__ __align__(16) short X[BM * XLD];
    __shared__ __align__(16) short H[BM * HLD];

    const short* W1p = g_Wpack;
    const short* W2p = g_Wpack + W1P_SHORTS;

    const int tid = threadIdx.x;
    const int w = tid >> 6;          // wave 0..7
    const int l = tid & 63;
    const int l16 = l & 15;
    const int lg = l >> 4;           // 0..3
    const int row0 = blockIdx.x * BM;

    float b1v[4], b2v[2];
#pragma unroll
    for (int j = 0; j < 4; ++j) b1v[j] = b1[(w * 4 + j) * 16 + l16];
#pragma unroll
    for (int j = 0; j < 2; ++j) b2v[j] = b2[(w * 2 + j) * 16 + l16];

    float hstep[2];
#pragma unroll
    for (int mt = 0; mt < 2; ++mt)
        hstep[mt] = dtp[row0 + mt * 16 + l16] * (1.0f / NSTEPS);

    f32x4 z[2][2];
#pragma unroll
    for (int mt = 0; mt < 2; ++mt)
#pragma unroll
        for (int j2 = 0; j2 < 2; ++j2)
            z[mt][j2] = *reinterpret_cast<const f32x4*>(
                &zt[(row0 + mt * 16 + l16) * LATENT + (w * 2 + j2) * 16 + lg * 4]);

    {
        int r = tid >> 4, c = tid & 15;   // 512 threads = 32 rows x 16 cols
        X[r * XLD + 256 + c] = f2bf(ut[(row0 + r) * UDIM + c]);
        X[r * XLD + 272 + c] = 0;
    }
#pragma unroll
    for (int mt = 0; mt < 2; ++mt)
#pragma unroll
        for (int j2 = 0; j2 < 2; ++j2) {
            bf16x4 p;
#pragma unroll
            for (int i = 0; i < 4; ++i) p[i] = f2bf(z[mt][j2][i]);
            *reinterpret_cast<bf16x4*>(&X[(mt * 16 + l16) * XLD + (w * 2 + j2) * 16 + lg * 4]) = p;
        }
    __syncthreads();

    // W1 burst for step 0 (flight overlaps nothing the first time; pinned below)
    bf16x8 wf1[36];
#pragma unroll
    for (int kt = 0; kt < 9; ++kt)
#pragma unroll
        for (int j = 0; j < 4; ++j)
            wf1[kt * 4 + j] = *reinterpret_cast<const bf16x8*>(
                &W1p[((kt * 32 + (w * 4 + j)) * 64 + l) * 8]);

#pragma unroll 1
    for (int t = 0; t < NSTEPS; ++t) {
        // drain point for the W1 burst (issued at end of previous iteration)
#pragma unroll
        for (int f = 0; f < 36; ++f) asm volatile("" : "+v"(wf1[f]));

        // ---- GEMM1: hidden^T = W1^T (regs) x X^T (LDS), K = 288
        f32x4 acc1[2][4];
#pragma unroll
        for (int mt = 0; mt < 2; ++mt)
#pragma unroll
            for (int j = 0; j < 4; ++j)
                acc1[mt][j] = (f32x4){b1v[j], b1v[j], b1v[j], b1v[j]};

#pragma unroll
        for (int kt = 0; kt < 9; ++kt) {
            bf16x8 xb0 = *reinterpret_cast<const bf16x8*>(&X[(0 * 16 + l16) * XLD + kt * 32 + lg * 8]);
            bf16x8 xb1 = *reinterpret_cast<const bf16x8*>(&X[(1 * 16 + l16) * XLD + kt * 32 + lg * 8]);
#pragma unroll
            for (int j = 0; j < 4; ++j) {
                acc1[0][j] = __builtin_amdgcn_mfma_f32_16x16x32_bf16(wf1[kt * 4 + j], xb0, acc1[0][j], 0, 0, 0);
                acc1[1][j] = __builtin_amdgcn_mfma_f32_16x16x32_bf16(wf1[kt * 4 + j], xb1, acc1[1][j], 0, 0, 0);
            }
        }

        // ---- W2 burst: issue now; flight overlaps tanh + H-write + barrier
        bf16x8 w2f[32];
#pragma unroll
        for (int kt = 0; kt < 16; ++kt)
#pragma unroll
            for (int j2 = 0; j2 < 2; ++j2)
                w2f[kt * 2 + j2] = *reinterpret_cast<const bf16x8*>(
                    &W2p[((kt * 16 + (w * 2 + j2)) * 64 + l) * 8]);

        // tanh + pack hidden into LDS (row-major [batchrow][hiddendim])
#pragma unroll
        for (int mt = 0; mt < 2; ++mt)
#pragma unroll
            for (int j = 0; j < 4; ++j) {
                bf16x4 p;
#pragma unroll
                for (int i = 0; i < 4; ++i) p[i] = f2bf(tanh_fast(acc1[mt][j][i]));
                *reinterpret_cast<bf16x4*>(&H[(mt * 16 + l16) * HLD + (w * 4 + j) * 16 + lg * 4]) = p;
            }
        __syncthreads();

        // drain point for the W2 burst
#pragma unroll
        for (int f = 0; f < 32; ++f) asm volatile("" : "+v"(w2f[f]));

        // ---- GEMM2: f^T = W2^T (regs) x hidden^T (LDS), K = 512
        f32x4 acc2[2][2];
#pragma unroll
        for (int mt = 0; mt < 2; ++mt)
#pragma unroll
            for (int j2 = 0; j2 < 2; ++j2)
                acc2[mt][j2] = (f32x4){b2v[j2], b2v[j2], b2v[j2], b2v[j2]};

#pragma unroll
        for (int kt = 0; kt < 16; ++kt) {
            bf16x8 hb0 = *reinterpret_cast<const bf16x8*>(&H[(0 * 16 + l16) * HLD + kt * 32 + lg * 8]);
            bf16x8 hb1 = *reinterpret_cast<const bf16x8*>(&H[(1 * 16 + l16) * HLD + kt * 32 + lg * 8]);
#pragma unroll
            for (int j2 = 0; j2 < 2; ++j2) {
                acc2[0][j2] = __builtin_amdgcn_mfma_f32_16x16x32_bf16(w2f[kt * 2 + j2], hb0, acc2[0][j2], 0, 0, 0);
                acc2[1][j2] = __builtin_amdgcn_mfma_f32_16x16x32_bf16(w2f[kt * 2 + j2], hb1, acc2[1][j2], 0, 0, 0);
            }
        }

        // ---- W1 burst for NEXT step: w2f now dead; flight overlaps
        // z-update + X-write + barrier
        if (t < NSTEPS - 1) {
#pragma unroll
            for (int kt = 0; kt < 9; ++kt)
#pragma unroll
                for (int j = 0; j < 4; ++j)
                    wf1[kt * 4 + j] = *reinterpret_cast<const bf16x8*>(
                        &W1p[((kt * 32 + (w * 4 + j)) * 64 + l) * 8]);
        }

        // z += h * f ; write z back to X (bf16) for next step
#pragma unroll
        for (int mt = 0; mt < 2; ++mt)
#pragma unroll
            for (int j2 = 0; j2 < 2; ++j2)
#pragma unroll
                for (int i = 0; i < 4; ++i)
                    z[mt][j2][i] += hstep[mt] * acc2[mt][j2][i];

        if (t < NSTEPS - 1) {
#pragma unroll
            for (int mt = 0; mt < 2; ++mt)
#pragma unroll
                for (int j2 = 0; j2 < 2; ++j2) {
                    bf16x4 p;
#pragma unroll
                    for (int i = 0; i < 4; ++i) p[i] = f2bf(z[mt][j2][i]);
                    *reinterpret_cast<bf16x4*>(&X[(mt * 16 + l16) * XLD + (w * 2 + j2) * 16 + lg * 4]) = p;
                }
            __syncthreads();
        }
    }

    // final store (f32)
#pragma unroll
    for (int mt = 0; mt < 2; ++mt)
#pragma unroll
        for (int j2 = 0; j2 < 2; ++j2)
            *reinterpret_cast<f32x4*>(
                &out[(row0 + mt * 16 + l16) * LATENT + (w * 2 + j2) * 16 + lg * 4]) = z[mt][j2];
}

extern "C" void kernel_launch(void* const* d_in, const int* in_sizes, int n_in,
                              void* d_out, int out_size, void* d_ws, size_t ws_size,
                              hipStream_t stream) {
    const float* zt = (const float*)d_in[0];
    const float* dtp = (const float*)d_in[1];
    const float* ut = (const float*)d_in[2];
    const float* W1 = (const float*)d_in[3];
    const float* b1 = (const float*)d_in[4];
    const float* W2 = (const float*)d_in[5];
    const float* b2 = (const float*)d_in[6];

    prep_weights<<<136, 256, 0, stream>>>(W1, W2);
    ode_kernel<<<BROWS / BM, 512, 0, stream>>>(zt, dtp, ut, b1, b2, (float*)d_out);
}

// Round 12
// 254.729 us; speedup vs baseline: 2.3083x; 2.3083x over previous
//
#include <hip/hip_runtime.h>
#include <hip/hip_bf16.h>

#define NSTEPS 20
#define BROWS  8192
#define LATENT 256
#define UDIM   16
#define HIDDEN 512
#define BM     64      // rows per block (r12: 32 -> 64; halves per-row weight traffic)
#define XLD    296     // LDS row stride (bf16) for X (b128-friendly)
#define HLD    536     // LDS row stride (bf16) for H (b128-friendly)

// packed-weight footprint (shorts)
#define W1P_SHORTS (9 * 32 * 64 * 8)     // 147456
#define W2P_SHORTS (16 * 16 * 64 * 8)    // 131072

// Packed weights in module-scope device memory (load-time allocation; no
// hipMalloc, no d_ws, no d_out aliasing). Re-packed from immutable W1/W2
// every call -> deterministic across graph replays.
__device__ __align__(16) short g_Wpack[W1P_SHORTS + W2P_SHORTS];

typedef __attribute__((ext_vector_type(8))) short bf16x8;
typedef __attribute__((ext_vector_type(4))) short bf16x4;
typedef __attribute__((ext_vector_type(4))) float f32x4;

__device__ __forceinline__ short f2bf(float x) {
    union { __hip_bfloat16 h; short s; } u;
    u.h = __float2bfloat16(x);
    return u.s;
}

__device__ __forceinline__ float tanh_fast(float x) {
    float e = __expf(2.0f * x);
    return 1.0f - 2.0f * __builtin_amdgcn_rcpf(e + 1.0f);
}

// Pack W1 (272x512, K zero-padded to 288) and W2 (512x256) into per-fragment
// order: frag(kt,nt): lane l holds W[k = kt*32 + (l>>4)*8 + j][n = nt*16 + (l&15)].
__global__ void prep_weights(const float* __restrict__ W1, const float* __restrict__ W2) {
    short* W1p = g_Wpack;
    short* W2p = g_Wpack + W1P_SHORTS;
    int t = blockIdx.x * 256 + threadIdx.x;
    if (t < 9 * 32 * 64) {
        int l = t & 63, f = t >> 6;          // f: 0..287 = kt*32+nt
        int kt = f >> 5, nt = f & 31;
        int k0 = kt * 32 + ((l >> 4) << 3);
        int n = nt * 16 + (l & 15);
        bf16x8 o;
#pragma unroll
        for (int j = 0; j < 8; ++j) {
            int k = k0 + j;
            o[j] = (k < 272) ? f2bf(W1[k * 512 + n]) : (short)0;
        }
        *reinterpret_cast<bf16x8*>(W1p + t * 8) = o;
    } else if (t < 9 * 32 * 64 + 16 * 16 * 64) {
        int t2 = t - 9 * 32 * 64;
        int l = t2 & 63, f = t2 >> 6;        // f: 0..255 = kt*16+nt
        int kt = f >> 4, nt = f & 15;
        int k0 = kt * 32 + ((l >> 4) << 3);
        int n = nt * 16 + (l & 15);
        bf16x8 o;
#pragma unroll
        for (int j = 0; j < 8; ++j) o[j] = f2bf(W2[(k0 + j) * 256 + n]);
        *reinterpret_cast<bf16x8*>(W2p + t2 * 8) = o;
    }
}

// One block = 64 rows, 16 waves (1024 threads), 1 block/CU, grid = 128.
// r12 theory: the 186us floor was the per-CU L2 weight stream (544 KB/step)
// running latency-bound at ~24 B/cyc with only 8 waves of TLP. 16 waves
// double the in-flight loads (-> ~48 B/cyc) while serving 2x the rows per
// block, so per-row weight traffic halves. Structure is r7's (per-kt sunk
// loads, no register pins -- the allocator hard-caps this kernel at 128
// arch VGPRs and spills anything bigger, proven r8/r10/r11).
// Wave w: GEMM1 computes hidden tiles nt in {2w, 2w+1} for all 4 row-tiles;
// GEMM2 computes latent tile w for all 4 row-tiles. z stays in f32 regs.
__global__ __launch_bounds__(1024, 1) void ode_kernel(
    const float* __restrict__ zt, const float* __restrict__ dtp,
    const float* __restrict__ ut, const float* __restrict__ b1,
    const float* __restrict__ b2, float* __restrict__ out) {
    __shared__ __align__(16) short X[BM * XLD];   // 37,888 B
    __shared__ __align__(16) short H[BM * HLD];   // 68,608 B  (total 106 KB < 160 KB)

    const short* W1p = g_Wpack;
    const short* W2p = g_Wpack + W1P_SHORTS;

    const int tid = threadIdx.x;
    const int w = tid >> 6;          // wave 0..15
    const int l = tid & 63;
    const int l16 = l & 15;
    const int lg = l >> 4;           // 0..3
    const int row0 = blockIdx.x * BM;

    // biases for this wave's output tiles
    float b1v[2], b2v;
#pragma unroll
    for (int jn = 0; jn < 2; ++jn) b1v[jn] = b1[(w * 2 + jn) * 16 + l16];
    b2v = b2[w * 16 + l16];

    // per-row step size h = dt/NSTEPS (row = row0 + mt*16 + l16, mt = 0..3)
    float hstep[4];
#pragma unroll
    for (int mt = 0; mt < 4; ++mt)
        hstep[mt] = dtp[row0 + mt * 16 + l16] * (1.0f / NSTEPS);

    // z registers: z[mt] = zt[row0+mt*16+l16][w*16 + lg*4 .. +3]
    f32x4 z[4];
#pragma unroll
    for (int mt = 0; mt < 4; ++mt)
        z[mt] = *reinterpret_cast<const f32x4*>(
            &zt[(row0 + mt * 16 + l16) * LATENT + w * 16 + lg * 4]);

    // init: ut columns (256..271) + zero pad (272..287) of X
    {
        int r = tid >> 4, c = tid & 15;   // 1024 threads = 64 rows x 16 cols
        X[r * XLD + 256 + c] = f2bf(ut[(row0 + r) * UDIM + c]);
        X[r * XLD + 272 + c] = 0;
    }
    // init: z columns of X (bf16); wave w owns latent tile w
#pragma unroll
    for (int mt = 0; mt < 4; ++mt) {
        bf16x4 p;
#pragma unroll
        for (int i = 0; i < 4; ++i) p[i] = f2bf(z[mt][i]);
        *reinterpret_cast<bf16x4*>(&X[(mt * 16 + l16) * XLD + w * 16 + lg * 4]) = p;
    }
    __syncthreads();

#pragma unroll 1
    for (int t = 0; t < NSTEPS; ++t) {
        // ---- GEMM1: hidden^T = W1^T (streamed) x X^T (LDS), K = 288
        f32x4 acc1[4][2];
#pragma unroll
        for (int mt = 0; mt < 4; ++mt)
#pragma unroll
            for (int jn = 0; jn < 2; ++jn)
                acc1[mt][jn] = (f32x4){b1v[jn], b1v[jn], b1v[jn], b1v[jn]};

#pragma unroll
        for (int kt = 0; kt < 9; ++kt) {
            bf16x8 wf[2];
#pragma unroll
            for (int jn = 0; jn < 2; ++jn)
                wf[jn] = *reinterpret_cast<const bf16x8*>(
                    &W1p[((kt * 32 + (w * 2 + jn)) * 64 + l) * 8]);
            bf16x8 xb[4];
#pragma unroll
            for (int mt = 0; mt < 4; ++mt)
                xb[mt] = *reinterpret_cast<const bf16x8*>(
                    &X[(mt * 16 + l16) * XLD + kt * 32 + lg * 8]);
#pragma unroll
            for (int mt = 0; mt < 4; ++mt)
#pragma unroll
                for (int jn = 0; jn < 2; ++jn)
                    acc1[mt][jn] = __builtin_amdgcn_mfma_f32_16x16x32_bf16(
                        wf[jn], xb[mt], acc1[mt][jn], 0, 0, 0);
        }

        // tanh + pack hidden into LDS (row-major [batchrow][hiddendim])
#pragma unroll
        for (int mt = 0; mt < 4; ++mt)
#pragma unroll
            for (int jn = 0; jn < 2; ++jn) {
                bf16x4 p;
#pragma unroll
                for (int i = 0; i < 4; ++i) p[i] = f2bf(tanh_fast(acc1[mt][jn][i]));
                *reinterpret_cast<bf16x4*>(
                    &H[(mt * 16 + l16) * HLD + (w * 2 + jn) * 16 + lg * 4]) = p;
            }
        __syncthreads();

        // ---- GEMM2: f^T = W2^T (streamed) x hidden^T (LDS), K = 512
        f32x4 acc2[4];
#pragma unroll
        for (int mt = 0; mt < 4; ++mt)
            acc2[mt] = (f32x4){b2v, b2v, b2v, b2v};

#pragma unroll
        for (int kt = 0; kt < 16; ++kt) {
            bf16x8 w2 = *reinterpret_cast<const bf16x8*>(
                &W2p[((kt * 16 + w) * 64 + l) * 8]);
            bf16x8 hb[4];
#pragma unroll
            for (int mt = 0; mt < 4; ++mt)
                hb[mt] = *reinterpret_cast<const bf16x8*>(
                    &H[(mt * 16 + l16) * HLD + kt * 32 + lg * 8]);
#pragma unroll
            for (int mt = 0; mt < 4; ++mt)
                acc2[mt] = __builtin_amdgcn_mfma_f32_16x16x32_bf16(
                    w2, hb[mt], acc2[mt], 0, 0, 0);
        }

        // z += h * f ; write z back to X (bf16) for next step
#pragma unroll
        for (int mt = 0; mt < 4; ++mt)
#pragma unroll
            for (int i = 0; i < 4; ++i)
                z[mt][i] += hstep[mt] * acc2[mt][i];

        if (t < NSTEPS - 1) {
#pragma unroll
            for (int mt = 0; mt < 4; ++mt) {
                bf16x4 p;
#pragma unroll
                for (int i = 0; i < 4; ++i) p[i] = f2bf(z[mt][i]);
                *reinterpret_cast<bf16x4*>(
                    &X[(mt * 16 + l16) * XLD + w * 16 + lg * 4]) = p;
            }
            __syncthreads();
        }
    }

    // final store (f32)
#pragma unroll
    for (int mt = 0; mt < 4; ++mt)
        *reinterpret_cast<f32x4*>(
            &out[(row0 + mt * 16 + l16) * LATENT + w * 16 + lg * 4]) = z[mt];
}

extern "C" void kernel_launch(void* const* d_in, const int* in_sizes, int n_in,
                              void* d_out, int out_size, void* d_ws, size_t ws_size,
                              hipStream_t stream) {
    const float* zt = (const float*)d_in[0];
    const float* dtp = (const float*)d_in[1];
    const float* ut = (const float*)d_in[2];
    const float* W1 = (const float*)d_in[3];
    const float* b1 = (const float*)d_in[4];
    const float* W2 = (const float*)d_in[5];
    const float* b2 = (const float*)d_in[6];

    prep_weights<<<136, 256, 0, stream>>>(W1, W2);
    ode_kernel<<<BROWS / BM, 1024, 0, stream>>>(zt, dtp, ut, b1, b2, (float*)d_out);
}

// Round 13
// 129.083 us; speedup vs baseline: 4.5551x; 1.9734x over previous
//
#include <hip/hip_runtime.h>
#include <hip/hip_bf16.h>

#define NSTEPS 20
#define BROWS  8192
#define LATENT 256
#define UDIM   16
#define HIDDEN 512
#define BM     32      // rows per block
#define XLD    296     // LDS row stride (bf16) for X (b128-friendly)
#define HLD    536     // LDS row stride (bf16) for H (b128-friendly)
#define NSLOT  12      // per-wave weight-ring slots (1 KB frags), 12-deep async

// packed-weight footprint (shorts)
#define W1P_SHORTS (9 * 32 * 64 * 8)     // 147456
#define W2P_SHORTS (16 * 16 * 64 * 8)    // 131072

// Packed weights in module-scope device memory; re-packed from immutable
// W1/W2 every call -> deterministic across graph replays.
__device__ __align__(16) short g_Wpack[W1P_SHORTS + W2P_SHORTS];

typedef __attribute__((ext_vector_type(8))) short bf16x8;
typedef __attribute__((ext_vector_type(4))) short bf16x4;
typedef __attribute__((ext_vector_type(4))) float f32x4;

typedef __attribute__((address_space(1))) const unsigned int gbl_u32;
typedef __attribute__((address_space(3))) unsigned int lds_u32;

__device__ __forceinline__ short f2bf(float x) {
    union { __hip_bfloat16 h; short s; } u;
    u.h = __float2bfloat16(x);
    return u.s;
}

__device__ __forceinline__ float tanh_fast(float x) {
    float e = __expf(2.0f * x);
    return 1.0f - 2.0f * __builtin_amdgcn_rcpf(e + 1.0f);
}

template <int N>
__device__ __forceinline__ void waitvm() {
    asm volatile("s_waitcnt vmcnt(%0)" :: "n"(N) : "memory");
    __builtin_amdgcn_sched_barrier(0);
}

// raw barrier: drains LDS ops only, leaves the global_load_lds queue alive
// (__syncthreads would emit s_waitcnt vmcnt(0) and kill the prefetch pipeline)
__device__ __forceinline__ void lds_barrier() {
    asm volatile("s_waitcnt lgkmcnt(0)" ::: "memory");
    __builtin_amdgcn_s_barrier();
}

// unified per-step frag stream F[0..67]: i<36 -> W1 frag (kt=i/4, j=i%4),
// i>=36 -> W2 frag (m=i-36: kt2=m/2, j2=m%2). Per-lane global address.
__device__ __forceinline__ const short* frag_gaddr(int i, const short* W1p,
                                                   const short* W2p, int w, int l) {
    if (i < 36) {
        int kt = i >> 2, j = i & 3;
        return W1p + (((kt * 32) + (w * 4 + j)) * 64 + l) * 8;
    } else {
        int m = i - 36;
        return W2p + ((((m >> 1) * 16) + (w * 2 + (m & 1))) * 64 + l) * 8;
    }
}

// Pack W1 (272x512, K zero-padded to 288) and W2 (512x256) into per-fragment
// order: frag(kt,nt): lane l holds W[k = kt*32 + (l>>4)*8 + j][n = nt*16 + (l&15)].
__global__ void prep_weights(const float* __restrict__ W1, const float* __restrict__ W2) {
    short* W1p = g_Wpack;
    short* W2p = g_Wpack + W1P_SHORTS;
    int t = blockIdx.x * 256 + threadIdx.x;
    if (t < 9 * 32 * 64) {
        int l = t & 63, f = t >> 6;          // f: 0..287 = kt*32+nt
        int kt = f >> 5, nt = f & 31;
        int k0 = kt * 32 + ((l >> 4) << 3);
        int n = nt * 16 + (l & 15);
        bf16x8 o;
#pragma unroll
        for (int j = 0; j < 8; ++j) {
            int k = k0 + j;
            o[j] = (k < 272) ? f2bf(W1[k * 512 + n]) : (short)0;
        }
        *reinterpret_cast<bf16x8*>(W1p + t * 8) = o;
    } else if (t < 9 * 32 * 64 + 16 * 16 * 64) {
        int t2 = t - 9 * 32 * 64;
        int l = t2 & 63, f = t2 >> 6;        // f: 0..255 = kt*16+nt
        int kt = f >> 4, nt = f & 15;
        int k0 = kt * 32 + ((l >> 4) << 3);
        int n = nt * 16 + (l & 15);
        bf16x8 o;
#pragma unroll
        for (int j = 0; j < 8; ++j) o[j] = f2bf(W2[(k0 + j) * 256 + n]);
        *reinterpret_cast<bf16x8*>(W2p + t2 * 8) = o;
    }
}

// r13: weights stream through per-wave 12-slot LDS rings via
// __builtin_amdgcn_global_load_lds (no VGPR dest -> 12 loads in flight vs 4),
// throttled by counted s_waitcnt vmcnt(N) that is NEVER drained to 0 in the
// loop. Raw s_barrier (lgkm-only drain) keeps the queue alive across the two
// per-step barriers. Ring is wave-private -> no barriers for weight staging.
__global__ __launch_bounds__(512, 2) void ode_kernel(
    const float* __restrict__ zt, const float* __restrict__ dtp,
    const float* __restrict__ ut, const float* __restrict__ b1,
    const float* __restrict__ b2, float* __restrict__ out) {
    __shared__ __align__(16) short X[BM * XLD];            // 18,944 B
    __shared__ __align__(16) short H[BM * HLD];            // 34,304 B
    __shared__ __align__(16) short Wring[8][NSLOT][512];   // 98,304 B (total 151,552)

    const short* W1p = g_Wpack;
    const short* W2p = g_Wpack + W1P_SHORTS;

    const int tid = threadIdx.x;
    const int w = tid >> 6;          // wave 0..7
    const int l = tid & 63;
    const int l16 = l & 15;
    const int lg = l >> 4;           // 0..3
    const int row0 = blockIdx.x * BM;

#define STAGE(i) __builtin_amdgcn_global_load_lds(                         \
        (gbl_u32*)(frag_gaddr((i), W1p, W2p, w, l)),                       \
        (lds_u32*)(&Wring[w][(i) % NSLOT][0]), 16, 0, 0)

    float b1v[4], b2v[2];
#pragma unroll
    for (int j = 0; j < 4; ++j) b1v[j] = b1[(w * 4 + j) * 16 + l16];
#pragma unroll
    for (int j = 0; j < 2; ++j) b2v[j] = b2[(w * 2 + j) * 16 + l16];

    float hstep[2];
#pragma unroll
    for (int mt = 0; mt < 2; ++mt)
        hstep[mt] = dtp[row0 + mt * 16 + l16] * (1.0f / NSTEPS);

    f32x4 z[2][2];
#pragma unroll
    for (int mt = 0; mt < 2; ++mt)
#pragma unroll
        for (int j2 = 0; j2 < 2; ++j2)
            z[mt][j2] = *reinterpret_cast<const f32x4*>(
                &zt[(row0 + mt * 16 + l16) * LATENT + (w * 2 + j2) * 16 + lg * 4]);

    {
        int r = tid >> 4, c = tid & 15;   // 512 threads = 32 rows x 16 cols
        X[r * XLD + 256 + c] = f2bf(ut[(row0 + r) * UDIM + c]);
        X[r * XLD + 272 + c] = 0;
    }
#pragma unroll
    for (int mt = 0; mt < 2; ++mt)
#pragma unroll
        for (int j2 = 0; j2 < 2; ++j2) {
            bf16x4 p;
#pragma unroll
            for (int i = 0; i < 4; ++i) p[i] = f2bf(z[mt][j2][i]);
            *reinterpret_cast<bf16x4*>(&X[(mt * 16 + l16) * XLD + (w * 2 + j2) * 16 + lg * 4]) = p;
        }

    // force scalar-input loads to complete so the vmcnt stream stays clean-ish
    asm volatile("" : "+v"(hstep[0]), "+v"(hstep[1]));
    asm volatile("" : "+v"(b1v[0]), "+v"(b1v[1]), "+v"(b1v[2]), "+v"(b1v[3]));
    asm volatile("" : "+v"(b2v[0]), "+v"(b2v[1]));

    // initial prologue: stage F[0..11] (W1 kt 0..2)
#pragma unroll
    for (int i2 = 0; i2 < 12; ++i2) STAGE(i2);

    lds_barrier();

#pragma unroll 1
    for (int t = 0; t < NSTEPS; ++t) {
        // ---- GEMM1: hidden^T = W1^T (LDS ring) x X^T (LDS), K = 288
        f32x4 acc1[2][4];
#pragma unroll
        for (int mt = 0; mt < 2; ++mt)
#pragma unroll
            for (int j = 0; j < 4; ++j)
                acc1[mt][j] = (f32x4){b1v[j], b1v[j], b1v[j], b1v[j]};

#pragma unroll
        for (int kt = 0; kt < 9; ++kt) {
            waitvm<8>();   // F[4kt..4kt+3] retired (12+4kt issued, keep 8 in flight)
            bf16x8 a0 = *reinterpret_cast<const bf16x8*>(&Wring[w][(4 * kt + 0) % NSLOT][l * 8]);
            bf16x8 a1 = *reinterpret_cast<const bf16x8*>(&Wring[w][(4 * kt + 1) % NSLOT][l * 8]);
            bf16x8 a2 = *reinterpret_cast<const bf16x8*>(&Wring[w][(4 * kt + 2) % NSLOT][l * 8]);
            bf16x8 a3 = *reinterpret_cast<const bf16x8*>(&Wring[w][(4 * kt + 3) % NSLOT][l * 8]);
            bf16x8 xb0 = *reinterpret_cast<const bf16x8*>(&X[(0 * 16 + l16) * XLD + kt * 32 + lg * 8]);
            bf16x8 xb1 = *reinterpret_cast<const bf16x8*>(&X[(1 * 16 + l16) * XLD + kt * 32 + lg * 8]);
            acc1[0][0] = __builtin_amdgcn_mfma_f32_16x16x32_bf16(a0, xb0, acc1[0][0], 0, 0, 0);
            acc1[1][0] = __builtin_amdgcn_mfma_f32_16x16x32_bf16(a0, xb1, acc1[1][0], 0, 0, 0);
            acc1[0][1] = __builtin_amdgcn_mfma_f32_16x16x32_bf16(a1, xb0, acc1[0][1], 0, 0, 0);
            acc1[1][1] = __builtin_amdgcn_mfma_f32_16x16x32_bf16(a1, xb1, acc1[1][1], 0, 0, 0);
            acc1[0][2] = __builtin_amdgcn_mfma_f32_16x16x32_bf16(a2, xb0, acc1[0][2], 0, 0, 0);
            acc1[1][2] = __builtin_amdgcn_mfma_f32_16x16x32_bf16(a2, xb1, acc1[1][2], 0, 0, 0);
            acc1[0][3] = __builtin_amdgcn_mfma_f32_16x16x32_bf16(a3, xb0, acc1[0][3], 0, 0, 0);
            acc1[1][3] = __builtin_amdgcn_mfma_f32_16x16x32_bf16(a3, xb1, acc1[1][3], 0, 0, 0);
            __builtin_amdgcn_sched_barrier(0);
            // issue F[12+4kt .. 15+4kt] (kt>=6 rolls into W2 frags)
            STAGE(12 + 4 * kt); STAGE(13 + 4 * kt); STAGE(14 + 4 * kt); STAGE(15 + 4 * kt);
        }

        // tanh + pack hidden into LDS
#pragma unroll
        for (int mt = 0; mt < 2; ++mt)
#pragma unroll
            for (int j = 0; j < 4; ++j) {
                bf16x4 p;
#pragma unroll
                for (int i = 0; i < 4; ++i) p[i] = f2bf(tanh_fast(acc1[mt][j][i]));
                *reinterpret_cast<bf16x4*>(&H[(mt * 16 + l16) * HLD + (w * 4 + j) * 16 + lg * 4]) = p;
            }
        lds_barrier();   // lgkm-only: weight queue stays in flight

        // ---- GEMM2: f^T = W2^T (LDS ring) x hidden^T (LDS), K = 512
        f32x4 acc2[2][2];
#pragma unroll
        for (int mt = 0; mt < 2; ++mt)
#pragma unroll
            for (int j2 = 0; j2 < 2; ++j2)
                acc2[mt][j2] = (f32x4){b2v[j2], b2v[j2], b2v[j2], b2v[j2]};

#define G2ITER(kt2, N) {                                                                        \
        waitvm<N>();                                                                            \
        bf16x8 a0 = *reinterpret_cast<const bf16x8*>(&Wring[w][(36 + 2 * (kt2)) % NSLOT][l * 8]); \
        bf16x8 a1 = *reinterpret_cast<const bf16x8*>(&Wring[w][(37 + 2 * (kt2)) % NSLOT][l * 8]); \
        bf16x8 hb0 = *reinterpret_cast<const bf16x8*>(&H[(0 * 16 + l16) * HLD + (kt2) * 32 + lg * 8]); \
        bf16x8 hb1 = *reinterpret_cast<const bf16x8*>(&H[(1 * 16 + l16) * HLD + (kt2) * 32 + lg * 8]); \
        acc2[0][0] = __builtin_amdgcn_mfma_f32_16x16x32_bf16(a0, hb0, acc2[0][0], 0, 0, 0);     \
        acc2[1][0] = __builtin_amdgcn_mfma_f32_16x16x32_bf16(a0, hb1, acc2[1][0], 0, 0, 0);     \
        acc2[0][1] = __builtin_amdgcn_mfma_f32_16x16x32_bf16(a1, hb0, acc2[0][1], 0, 0, 0);     \
        acc2[1][1] = __builtin_amdgcn_mfma_f32_16x16x32_bf16(a1, hb1, acc2[1][1], 0, 0, 0);     \
        __builtin_amdgcn_sched_barrier(0);                                                      \
        if ((kt2) <= 9) { STAGE(48 + 2 * (kt2)); STAGE(49 + 2 * (kt2)); }                       \
    }

#pragma unroll
        for (int kt2 = 0; kt2 < 11; ++kt2) G2ITER(kt2, 10);
        G2ITER(11, 8); G2ITER(12, 6); G2ITER(13, 4); G2ITER(14, 2); G2ITER(15, 0);
#undef G2ITER

        // next step's W1 prologue: issue now, flight overlaps epilogue+barrier
        if (t < NSTEPS - 1) {
#pragma unroll
            for (int i2 = 0; i2 < 12; ++i2) STAGE(i2);
        }

        // z += h * f ; write z back to X (bf16) for next step
#pragma unroll
        for (int mt = 0; mt < 2; ++mt)
#pragma unroll
            for (int j2 = 0; j2 < 2; ++j2)
#pragma unroll
                for (int i = 0; i < 4; ++i)
                    z[mt][j2][i] += hstep[mt] * acc2[mt][j2][i];

        if (t < NSTEPS - 1) {
#pragma unroll
            for (int mt = 0; mt < 2; ++mt)
#pragma unroll
                for (int j2 = 0; j2 < 2; ++j2) {
                    bf16x4 p;
#pragma unroll
                    for (int i = 0; i < 4; ++i) p[i] = f2bf(z[mt][j2][i]);
                    *reinterpret_cast<bf16x4*>(&X[(mt * 16 + l16) * XLD + (w * 2 + j2) * 16 + lg * 4]) = p;
                }
            lds_barrier();
        }
    }

    // final store (f32)
#pragma unroll
    for (int mt = 0; mt < 2; ++mt)
#pragma unroll
        for (int j2 = 0; j2 < 2; ++j2)
            *reinterpret_cast<f32x4*>(
                &out[(row0 + mt * 16 + l16) * LATENT + (w * 2 + j2) * 16 + lg * 4]) = z[mt][j2];
#undef STAGE
}

extern "C" void kernel_launch(void* const* d_in, const int* in_sizes, int n_in,
                              void* d_out, int out_size, void* d_ws, size_t ws_size,
                              hipStream_t stream) {
    const float* zt = (const float*)d_in[0];
    const float* dtp = (const float*)d_in[1];
    const float* ut = (const float*)d_in[2];
    const float* W1 = (const float*)d_in[3];
    const float* b1 = (const float*)d_in[4];
    const float* W2 = (const float*)d_in[5];
    const float* b2 = (const float*)d_in[6];

    prep_weights<<<136, 256, 0, stream>>>(W1, W2);
    ode_kernel<<<BROWS / BM, 512, 0, stream>>>(zt, dtp, ut, b1, b2, (float*)d_out);
}

// Round 14
// 118.779 us; speedup vs baseline: 4.9502x; 1.0867x over previous
//
#include <hip/hip_runtime.h>
#include <hip/hip_bf16.h>

#define NSTEPS 20
#define BROWS  8192
#define LATENT 256
#define UDIM   16
#define HIDDEN 512
#define BM     32      // rows per block
#define XLD    296     // LDS row stride (bf16) for X
#define HLD    536     // LDS row stride (bf16) for H

// packed-weight footprint (shorts)
#define W1P_SHORTS (9 * 32 * 64 * 8)     // 147456
#define W2P_SHORTS (16 * 16 * 64 * 8)    // 131072

// Packed weights in module-scope device memory; re-packed from immutable
// W1/W2 every call -> deterministic across graph replays.
__device__ __align__(16) short g_Wpack[W1P_SHORTS + W2P_SHORTS];

typedef __attribute__((ext_vector_type(8))) short bf16x8;
typedef __attribute__((ext_vector_type(4))) short bf16x4;
typedef __attribute__((ext_vector_type(4))) float f32x4;

__device__ __forceinline__ short f2bf(float x) {
    union { __hip_bfloat16 h; short s; } u;
    u.h = __float2bfloat16(x);
    return u.s;
}

__device__ __forceinline__ float tanh_fast(float x) {
    float e = __expf(2.0f * x);
    return 1.0f - 2.0f * __builtin_amdgcn_rcpf(e + 1.0f);
}

// raw barrier: drains LDS ops only; leaves the global-load queue alive
// (__syncthreads would emit s_waitcnt vmcnt(0) and kill the weight pipeline)
__device__ __forceinline__ void lds_barrier() {
    asm volatile("s_waitcnt lgkmcnt(0)" ::: "memory");
    __builtin_amdgcn_s_barrier();
}

// W1 fragment (kt, nt): lane l holds 8 contiguous bf16 at this address
__device__ __forceinline__ const bf16x8* w1_frag(const short* W1p, int kt, int nt, int l) {
    return reinterpret_cast<const bf16x8*>(W1p + ((kt * 32 + nt) * 64 + l) * 8);
}
__device__ __forceinline__ const bf16x8* w2_frag(const short* W2p, int kt2, int nt, int l) {
    return reinterpret_cast<const bf16x8*>(W2p + ((kt2 * 16 + nt) * 64 + l) * 8);
}

// Pack W1 (272x512, K zero-padded to 288) and W2 (512x256) into per-fragment
// order: frag(kt,nt): lane l holds W[k = kt*32 + (l>>4)*8 + j][n = nt*16 + (l&15)].
__global__ void prep_weights(const float* __restrict__ W1, const float* __restrict__ W2) {
    short* W1p = g_Wpack;
    short* W2p = g_Wpack + W1P_SHORTS;
    int t = blockIdx.x * 256 + threadIdx.x;
    if (t < 9 * 32 * 64) {
        int l = t & 63, f = t >> 6;          // f: 0..287 = kt*32+nt
        int kt = f >> 5, nt = f & 31;
        int k0 = kt * 32 + ((l >> 4) << 3);
        int n = nt * 16 + (l & 15);
        bf16x8 o;
#pragma unroll
        for (int j = 0; j < 8; ++j) {
            int k = k0 + j;
            o[j] = (k < 272) ? f2bf(W1[k * 512 + n]) : (short)0;
        }
        *reinterpret_cast<bf16x8*>(W1p + t * 8) = o;
    } else if (t < 9 * 32 * 64 + 16 * 16 * 64) {
        int t2 = t - 9 * 32 * 64;
        int l = t2 & 63, f = t2 >> 6;        // f: 0..255 = kt*16+nt
        int kt = f >> 4, nt = f & 15;
        int k0 = kt * 32 + ((l >> 4) << 3);
        int n = nt * 16 + (l & 15);
        bf16x8 o;
#pragma unroll
        for (int j = 0; j < 8; ++j) o[j] = f2bf(W2[(k0 + j) * 256 + n]);
        *reinterpret_cast<bf16x8*>(W2p + t2 * 8) = o;
    }
}

// r14: weights stream global->VGPR (zero LDS traffic for weights; r13's ring
// made the LDS unit the bottleneck at ~1.5 MB/step/CU). Double-buffered
// 1-iteration-ahead loads, pinned EARLY via sched_barrier(0) so the compiler
// emits counted vmcnt (not drain-0 next to the use, r7's failure). GEMM2's
// first frags issue before tanh; next step's first W1 frags issue at kt2==13.
// Raw lgkm-only barriers keep the global queue alive across phases.
__global__ __launch_bounds__(512, 2) void ode_kernel(
    const float* __restrict__ zt, const float* __restrict__ dtp,
    const float* __restrict__ ut, const float* __restrict__ b1,
    const float* __restrict__ b2, float* __restrict__ out) {
    __shared__ __align__(16) short X[BM * XLD];   // 18,944 B
    __shared__ __align__(16) short H[BM * HLD];   // 34,304 B

    const short* W1p = g_Wpack;
    const short* W2p = g_Wpack + W1P_SHORTS;

    const int tid = threadIdx.x;
    const int w = tid >> 6;          // wave 0..7
    const int l = tid & 63;
    const int l16 = l & 15;
    const int lg = l >> 4;           // 0..3
    const int row0 = blockIdx.x * BM;

    float b1v[4], b2v[2];
#pragma unroll
    for (int j = 0; j < 4; ++j) b1v[j] = b1[(w * 4 + j) * 16 + l16];
#pragma unroll
    for (int j = 0; j < 2; ++j) b2v[j] = b2[(w * 2 + j) * 16 + l16];

    float hstep[2];
#pragma unroll
    for (int mt = 0; mt < 2; ++mt)
        hstep[mt] = dtp[row0 + mt * 16 + l16] * (1.0f / NSTEPS);

    f32x4 z[2][2];
#pragma unroll
    for (int mt = 0; mt < 2; ++mt)
#pragma unroll
        for (int j2 = 0; j2 < 2; ++j2)
            z[mt][j2] = *reinterpret_cast<const f32x4*>(
                &zt[(row0 + mt * 16 + l16) * LATENT + (w * 2 + j2) * 16 + lg * 4]);

    {
        int r = tid >> 4, c = tid & 15;   // 512 threads = 32 rows x 16 cols
        X[r * XLD + 256 + c] = f2bf(ut[(row0 + r) * UDIM + c]);
        X[r * XLD + 272 + c] = 0;
    }
#pragma unroll
    for (int mt = 0; mt < 2; ++mt)
#pragma unroll
        for (int j2 = 0; j2 < 2; ++j2) {
            bf16x4 p;
#pragma unroll
            for (int i = 0; i < 4; ++i) p[i] = f2bf(z[mt][j2][i]);
            *reinterpret_cast<bf16x4*>(&X[(mt * 16 + l16) * XLD + (w * 2 + j2) * 16 + lg * 4]) = p;
        }

    // W1 kt=0 fragments for step 0 (in flight across the barrier)
    bf16x8 wf[2][4];
#pragma unroll
    for (int j = 0; j < 4; ++j) wf[0][j] = *w1_frag(W1p, 0, w * 4 + j, l);

    lds_barrier();

#pragma unroll 1
    for (int t = 0; t < NSTEPS; ++t) {
        // ---- GEMM1: hidden^T = W1^T (VGPR stream) x X^T (LDS), K = 288
        f32x4 acc1[2][4];
#pragma unroll
        for (int mt = 0; mt < 2; ++mt)
#pragma unroll
            for (int j = 0; j < 4; ++j)
                acc1[mt][j] = (f32x4){b1v[j], b1v[j], b1v[j], b1v[j]};

#pragma unroll
        for (int kt = 0; kt < 9; ++kt) {
            if (kt < 8) {
#pragma unroll
                for (int j = 0; j < 4; ++j)
                    wf[(kt + 1) & 1][j] = *w1_frag(W1p, kt + 1, w * 4 + j, l);
            }
            __builtin_amdgcn_sched_barrier(0);   // loads issue BEFORE this kt's MFMAs
            bf16x8 xb0 = *reinterpret_cast<const bf16x8*>(&X[(0 * 16 + l16) * XLD + kt * 32 + lg * 8]);
            bf16x8 xb1 = *reinterpret_cast<const bf16x8*>(&X[(1 * 16 + l16) * XLD + kt * 32 + lg * 8]);
#pragma unroll
            for (int j = 0; j < 4; ++j) {
                acc1[0][j] = __builtin_amdgcn_mfma_f32_16x16x32_bf16(wf[kt & 1][j], xb0, acc1[0][j], 0, 0, 0);
                acc1[1][j] = __builtin_amdgcn_mfma_f32_16x16x32_bf16(wf[kt & 1][j], xb1, acc1[1][j], 0, 0, 0);
            }
        }

        // GEMM2 prologue: kt2=0 fragments issue now; latency hides under
        // tanh + H-write + barrier
        bf16x8 w2b[2][2];
#pragma unroll
        for (int j2 = 0; j2 < 2; ++j2) w2b[0][j2] = *w2_frag(W2p, 0, w * 2 + j2, l);
        __builtin_amdgcn_sched_barrier(0);

        // tanh + pack hidden into LDS
#pragma unroll
        for (int mt = 0; mt < 2; ++mt)
#pragma unroll
            for (int j = 0; j < 4; ++j) {
                bf16x4 p;
#pragma unroll
                for (int i = 0; i < 4; ++i) p[i] = f2bf(tanh_fast(acc1[mt][j][i]));
                *reinterpret_cast<bf16x4*>(&H[(mt * 16 + l16) * HLD + (w * 4 + j) * 16 + lg * 4]) = p;
            }
        lds_barrier();   // lgkm-only: weight loads stay in flight

        // ---- GEMM2: f^T = W2^T (VGPR stream) x hidden^T (LDS), K = 512
        f32x4 acc2[2][2];
#pragma unroll
        for (int mt = 0; mt < 2; ++mt)
#pragma unroll
            for (int j2 = 0; j2 < 2; ++j2)
                acc2[mt][j2] = (f32x4){b2v[j2], b2v[j2], b2v[j2], b2v[j2]};

#pragma unroll
        for (int kt2 = 0; kt2 < 16; ++kt2) {
            if (kt2 < 15) {
#pragma unroll
                for (int j2 = 0; j2 < 2; ++j2)
                    w2b[(kt2 + 1) & 1][j2] = *w2_frag(W2p, kt2 + 1, w * 2 + j2, l);
            }
            if (kt2 == 13) {
                // next step's W1 kt=0: flight hides under GEMM2 tail +
                // epilogue + barrier (issued unconditionally; dead at t=19)
#pragma unroll
                for (int j = 0; j < 4; ++j)
                    wf[0][j] = *w1_frag(W1p, 0, w * 4 + j, l);
            }
            __builtin_amdgcn_sched_barrier(0);
            bf16x8 hb0 = *reinterpret_cast<const bf16x8*>(&H[(0 * 16 + l16) * HLD + kt2 * 32 + lg * 8]);
            bf16x8 hb1 = *reinterpret_cast<const bf16x8*>(&H[(1 * 16 + l16) * HLD + kt2 * 32 + lg * 8]);
#pragma unroll
            for (int j2 = 0; j2 < 2; ++j2) {
                acc2[0][j2] = __builtin_amdgcn_mfma_f32_16x16x32_bf16(w2b[kt2 & 1][j2], hb0, acc2[0][j2], 0, 0, 0);
                acc2[1][j2] = __builtin_amdgcn_mfma_f32_16x16x32_bf16(w2b[kt2 & 1][j2], hb1, acc2[1][j2], 0, 0, 0);
            }
        }

        // z += h * f ; write z back to X (bf16) for next step
#pragma unroll
        for (int mt = 0; mt < 2; ++mt)
#pragma unroll
            for (int j2 = 0; j2 < 2; ++j2)
#pragma unroll
                for (int i = 0; i < 4; ++i)
                    z[mt][j2][i] += hstep[mt] * acc2[mt][j2][i];

        if (t < NSTEPS - 1) {
#pragma unroll
            for (int mt = 0; mt < 2; ++mt)
#pragma unroll
                for (int j2 = 0; j2 < 2; ++j2) {
                    bf16x4 p;
#pragma unroll
                    for (int i = 0; i < 4; ++i) p[i] = f2bf(z[mt][j2][i]);
                    *reinterpret_cast<bf16x4*>(&X[(mt * 16 + l16) * XLD + (w * 2 + j2) * 16 + lg * 4]) = p;
                }
            lds_barrier();
        }
    }

    // final store (f32)
#pragma unroll
    for (int mt = 0; mt < 2; ++mt)
#pragma unroll
        for (int j2 = 0; j2 < 2; ++j2)
            *reinterpret_cast<f32x4*>(
                &out[(row0 + mt * 16 + l16) * LATENT + (w * 2 + j2) * 16 + lg * 4]) = z[mt][j2];
}

extern "C" void kernel_launch(void* const* d_in, const int* in_sizes, int n_in,
                              void* d_out, int out_size, void* d_ws, size_t ws_size,
                              hipStream_t stream) {
    const float* zt = (const float*)d_in[0];
    const float* dtp = (const float*)d_in[1];
    const float* ut = (const float*)d_in[2];
    const float* W1 = (const float*)d_in[3];
    const float* b1 = (const float*)d_in[4];
    const float* W2 = (const float*)d_in[5];
    const float* b2 = (const float*)d_in[6];

    prep_weights<<<136, 256, 0, stream>>>(W1, W2);
    ode_kernel<<<BROWS / BM, 512, 0, stream>>>(zt, dtp, ut, b1, b2, (float*)d_out);
}

// Round 15
// 113.614 us; speedup vs baseline: 5.1753x; 1.0455x over previous
//
#include <hip/hip_runtime.h>
#include <hip/hip_bf16.h>

#define NSTEPS 20
#define BROWS  8192
#define LATENT 256
#define UDIM   16
#define HIDDEN 512
#define BM     32      // rows per block
#define XLD    296     // LDS row stride (bf16) for X
#define HLD    536     // LDS row stride (bf16) for H
#define NKC    3       // W1 kt-tiles cached in LDS (kt = 0..NKC-1)

// packed-weight footprint (shorts)
#define W1P_SHORTS (9 * 32 * 64 * 8)     // 147456
#define W2P_SHORTS (16 * 16 * 64 * 8)    // 131072

// Packed weights in module-scope device memory; re-packed from immutable
// W1/W2 every call -> deterministic across graph replays.
__device__ __align__(16) short g_Wpack[W1P_SHORTS + W2P_SHORTS];

typedef __attribute__((ext_vector_type(8))) short bf16x8;
typedef __attribute__((ext_vector_type(4))) short bf16x4;
typedef __attribute__((ext_vector_type(4))) float f32x4;

typedef __attribute__((address_space(1))) const unsigned int gbl_u32;
typedef __attribute__((address_space(3))) unsigned int lds_u32;

__device__ __forceinline__ short f2bf(float x) {
    union { __hip_bfloat16 h; short s; } u;
    u.h = __float2bfloat16(x);
    return u.s;
}

__device__ __forceinline__ float tanh_fast(float x) {
    float e = __expf(2.0f * x);
    return 1.0f - 2.0f * __builtin_amdgcn_rcpf(e + 1.0f);
}

// raw barrier: drains LDS ops only; leaves the global-load queue alive
__device__ __forceinline__ void lds_barrier() {
    asm volatile("s_waitcnt lgkmcnt(0)" ::: "memory");
    __builtin_amdgcn_s_barrier();
}

__device__ __forceinline__ const bf16x8* w1_frag(const short* W1p, int kt, int nt, int l) {
    return reinterpret_cast<const bf16x8*>(W1p + ((kt * 32 + nt) * 64 + l) * 8);
}
__device__ __forceinline__ const bf16x8* w2_frag(const short* W2p, int kt2, int nt, int l) {
    return reinterpret_cast<const bf16x8*>(W2p + ((kt2 * 16 + nt) * 64 + l) * 8);
}

// Pack W1 (272x512, K zero-padded to 288) and W2 (512x256) into per-fragment
// order: frag(kt,nt): lane l holds W[k = kt*32 + (l>>4)*8 + j][n = nt*16 + (l&15)].
__global__ void prep_weights(const float* __restrict__ W1, const float* __restrict__ W2) {
    short* W1p = g_Wpack;
    short* W2p = g_Wpack + W1P_SHORTS;
    int t = blockIdx.x * 256 + threadIdx.x;
    if (t < 9 * 32 * 64) {
        int l = t & 63, f = t >> 6;          // f: 0..287 = kt*32+nt
        int kt = f >> 5, nt = f & 31;
        int k0 = kt * 32 + ((l >> 4) << 3);
        int n = nt * 16 + (l & 15);
        bf16x8 o;
#pragma unroll
        for (int j = 0; j < 8; ++j) {
            int k = k0 + j;
            o[j] = (k < 272) ? f2bf(W1[k * 512 + n]) : (short)0;
        }
        *reinterpret_cast<bf16x8*>(W1p + t * 8) = o;
    } else if (t < 9 * 32 * 64 + 16 * 16 * 64) {
        int t2 = t - 9 * 32 * 64;
        int l = t2 & 63, f = t2 >> 6;        // f: 0..255 = kt*16+nt
        int kt = f >> 4, nt = f & 15;
        int k0 = kt * 32 + ((l >> 4) << 3);
        int n = nt * 16 + (l & 15);
        bf16x8 o;
#pragma unroll
        for (int j = 0; j < 8; ++j) o[j] = f2bf(W2[(k0 + j) * 256 + n]);
        *reinterpret_cast<bf16x8*>(W2p + t2 * 8) = o;
    }
}

// r15: r14's global->VGPR stream, plus:
//  (1) W1 kt=0..2 held in wave-private LDS for the whole kernel (96 KB that
//      was idle) -> streamed bytes 544->448 KB/step and GEMM1's post-barrier
//      cold start is LDS-fed while the kt=3/4 loads get a 2-3 iter head start.
//  (2) TRUE 2-ahead double buffers at zero extra VGPRs: consume wf[kt&1]
//      then immediately reload it with kt+2 (WAR safe: load writeback >> MFMA
//      operand read). GEMM2 prologue issues kt2={0,1} before tanh.
__global__ __launch_bounds__(512, 2) void ode_kernel(
    const float* __restrict__ zt, const float* __restrict__ dtp,
    const float* __restrict__ ut, const float* __restrict__ b1,
    const float* __restrict__ b2, float* __restrict__ out) {
    __shared__ __align__(16) short X[BM * XLD];            // 18,944 B
    __shared__ __align__(16) short H[BM * HLD];            // 34,304 B
    __shared__ __align__(16) short W1c[8][NKC][4][512];    // 98,304 B (151,552 total)

    const short* W1p = g_Wpack;
    const short* W2p = g_Wpack + W1P_SHORTS;

    const int tid = threadIdx.x;
    const int w = tid >> 6;          // wave 0..7
    const int l = tid & 63;
    const int l16 = l & 15;
    const int lg = l >> 4;           // 0..3
    const int row0 = blockIdx.x * BM;

    // stage the persistent W1 cache FIRST (12 gload_lds per wave, no VGPR dest)
#pragma unroll
    for (int kt = 0; kt < NKC; ++kt)
#pragma unroll
        for (int j = 0; j < 4; ++j)
            __builtin_amdgcn_global_load_lds(
                (gbl_u32*)w1_frag(W1p, kt, w * 4 + j, l),
                (lds_u32*)&W1c[w][kt][j][0], 16, 0, 0);

    float b1v[4], b2v[2];
#pragma unroll
    for (int j = 0; j < 4; ++j) b1v[j] = b1[(w * 4 + j) * 16 + l16];
#pragma unroll
    for (int j = 0; j < 2; ++j) b2v[j] = b2[(w * 2 + j) * 16 + l16];

    float hstep[2];
#pragma unroll
    for (int mt = 0; mt < 2; ++mt)
        hstep[mt] = dtp[row0 + mt * 16 + l16] * (1.0f / NSTEPS);

    f32x4 z[2][2];
#pragma unroll
    for (int mt = 0; mt < 2; ++mt)
#pragma unroll
        for (int j2 = 0; j2 < 2; ++j2)
            z[mt][j2] = *reinterpret_cast<const f32x4*>(
                &zt[(row0 + mt * 16 + l16) * LATENT + (w * 2 + j2) * 16 + lg * 4]);

    {
        int r = tid >> 4, c = tid & 15;   // 512 threads = 32 rows x 16 cols
        X[r * XLD + 256 + c] = f2bf(ut[(row0 + r) * UDIM + c]);
        X[r * XLD + 272 + c] = 0;
    }
#pragma unroll
    for (int mt = 0; mt < 2; ++mt)
#pragma unroll
        for (int j2 = 0; j2 < 2; ++j2) {
            bf16x4 p;
#pragma unroll
            for (int i = 0; i < 4; ++i) p[i] = f2bf(z[mt][j2][i]);
            *reinterpret_cast<bf16x4*>(&X[(mt * 16 + l16) * XLD + (w * 2 + j2) * 16 + lg * 4]) = p;
        }

    // W1c staged + all scalar loads done before the loop
    asm volatile("s_waitcnt vmcnt(0)" ::: "memory");
    lds_barrier();

    bf16x8 wf[2][4];     // streamed-W1 double buffer (kt = 3..8)
    bf16x8 w2b[2][2];    // streamed-W2 double buffer

#pragma unroll 1
    for (int t = 0; t < NSTEPS; ++t) {
        // ---- GEMM1: hidden^T = W1^T x X^T, K = 288 (kt 0..2 LDS, 3..8 stream)
        f32x4 acc1[2][4];
#pragma unroll
        for (int mt = 0; mt < 2; ++mt)
#pragma unroll
            for (int j = 0; j < 4; ++j)
                acc1[mt][j] = (f32x4){b1v[j], b1v[j], b1v[j], b1v[j]};

#pragma unroll
        for (int kt = 0; kt < 9; ++kt) {
            if (kt == 0) {   // kt=3's frags: 3-iteration lead
#pragma unroll
                for (int j = 0; j < 4; ++j) wf[1][j] = *w1_frag(W1p, 3, w * 4 + j, l);
            }
            if (kt == 2) {   // kt=4's frags: 2-iteration lead
#pragma unroll
                for (int j = 0; j < 4; ++j) wf[0][j] = *w1_frag(W1p, 4, w * 4 + j, l);
            }
            __builtin_amdgcn_sched_barrier(0);
            bf16x8 a[4];
            if (kt < NKC) {
#pragma unroll
                for (int j = 0; j < 4; ++j)
                    a[j] = *reinterpret_cast<const bf16x8*>(&W1c[w][kt][j][l * 8]);
            } else {
#pragma unroll
                for (int j = 0; j < 4; ++j) a[j] = wf[kt & 1][j];
            }
            bf16x8 xb0 = *reinterpret_cast<const bf16x8*>(&X[(0 * 16 + l16) * XLD + kt * 32 + lg * 8]);
            bf16x8 xb1 = *reinterpret_cast<const bf16x8*>(&X[(1 * 16 + l16) * XLD + kt * 32 + lg * 8]);
#pragma unroll
            for (int j = 0; j < 4; ++j) {
                acc1[0][j] = __builtin_amdgcn_mfma_f32_16x16x32_bf16(a[j], xb0, acc1[0][j], 0, 0, 0);
                acc1[1][j] = __builtin_amdgcn_mfma_f32_16x16x32_bf16(a[j], xb1, acc1[1][j], 0, 0, 0);
            }
            __builtin_amdgcn_sched_barrier(0);
            if (kt >= 3 && kt + 2 < 9) {   // refill the just-consumed buffer with kt+2
#pragma unroll
                for (int j = 0; j < 4; ++j)
                    wf[kt & 1][j] = *w1_frag(W1p, kt + 2, w * 4 + j, l);
            }
        }

        // GEMM2 prologue: kt2=0,1 issue now; latency hides under tanh + barrier
#pragma unroll
        for (int j2 = 0; j2 < 2; ++j2) {
            w2b[0][j2] = *w2_frag(W2p, 0, w * 2 + j2, l);
            w2b[1][j2] = *w2_frag(W2p, 1, w * 2 + j2, l);
        }
        __builtin_amdgcn_sched_barrier(0);

        // tanh + pack hidden into LDS
#pragma unroll
        for (int mt = 0; mt < 2; ++mt)
#pragma unroll
            for (int j = 0; j < 4; ++j) {
                bf16x4 p;
#pragma unroll
                for (int i = 0; i < 4; ++i) p[i] = f2bf(tanh_fast(acc1[mt][j][i]));
                *reinterpret_cast<bf16x4*>(&H[(mt * 16 + l16) * HLD + (w * 4 + j) * 16 + lg * 4]) = p;
            }
        lds_barrier();   // lgkm-only: weight loads stay in flight

        // ---- GEMM2: f^T = W2^T (VGPR stream, 2-ahead) x hidden^T (LDS), K = 512
        f32x4 acc2[2][2];
#pragma unroll
        for (int mt = 0; mt < 2; ++mt)
#pragma unroll
            for (int j2 = 0; j2 < 2; ++j2)
                acc2[mt][j2] = (f32x4){b2v[j2], b2v[j2], b2v[j2], b2v[j2]};

#pragma unroll
        for (int kt2 = 0; kt2 < 16; ++kt2) {
            bf16x8 hb0 = *reinterpret_cast<const bf16x8*>(&H[(0 * 16 + l16) * HLD + kt2 * 32 + lg * 8]);
            bf16x8 hb1 = *reinterpret_cast<const bf16x8*>(&H[(1 * 16 + l16) * HLD + kt2 * 32 + lg * 8]);
#pragma unroll
            for (int j2 = 0; j2 < 2; ++j2) {
                acc2[0][j2] = __builtin_amdgcn_mfma_f32_16x16x32_bf16(w2b[kt2 & 1][j2], hb0, acc2[0][j2], 0, 0, 0);
                acc2[1][j2] = __builtin_amdgcn_mfma_f32_16x16x32_bf16(w2b[kt2 & 1][j2], hb1, acc2[1][j2], 0, 0, 0);
            }
            __builtin_amdgcn_sched_barrier(0);
            if (kt2 + 2 < 16) {   // refill the just-consumed buffer with kt2+2
#pragma unroll
                for (int j2 = 0; j2 < 2; ++j2)
                    w2b[kt2 & 1][j2] = *w2_frag(W2p, kt2 + 2, w * 2 + j2, l);
            }
        }

        // z += h * f ; write z back to X (bf16) for next step
#pragma unroll
        for (int mt = 0; mt < 2; ++mt)
#pragma unroll
            for (int j2 = 0; j2 < 2; ++j2)
#pragma unroll
                for (int i = 0; i < 4; ++i)
                    z[mt][j2][i] += hstep[mt] * acc2[mt][j2][i];

        if (t < NSTEPS - 1) {
#pragma unroll
            for (int mt = 0; mt < 2; ++mt)
#pragma unroll
                for (int j2 = 0; j2 < 2; ++j2) {
                    bf16x4 p;
#pragma unroll
                    for (int i = 0; i < 4; ++i) p[i] = f2bf(z[mt][j2][i]);
                    *reinterpret_cast<bf16x4*>(&X[(mt * 16 + l16) * XLD + (w * 2 + j2) * 16 + lg * 4]) = p;
                }
            lds_barrier();
        }
    }

    // final store (f32)
#pragma unroll
    for (int mt = 0; mt < 2; ++mt)
#pragma unroll
        for (int j2 = 0; j2 < 2; ++j2)
            *reinterpret_cast<f32x4*>(
                &out[(row0 + mt * 16 + l16) * LATENT + (w * 2 + j2) * 16 + lg * 4]) = z[mt][j2];
}

extern "C" void kernel_launch(void* const* d_in, const int* in_sizes, int n_in,
                              void* d_out, int out_size, void* d_ws, size_t ws_size,
                              hipStream_t stream) {
    const float* zt = (const float*)d_in[0];
    const float* dtp = (const float*)d_in[1];
    const float* ut = (const float*)d_in[2];
    const float* W1 = (const float*)d_in[3];
    const float* b1 = (const float*)d_in[4];
    const float* W2 = (const float*)d_in[5];
    const float* b2 = (const float*)d_in[6];

    prep_weights<<<136, 256, 0, stream>>>(W1, W2);
    ode_kernel<<<BROWS / BM, 512, 0, stream>>>(zt, dtp, ut, b1, b2, (float*)d_out);
}